// Round 17
// baseline (315.890 us; speedup 1.0000x reference)
//
#include <hip/hip_runtime.h>
#include <cstdint>
#include <cstddef>

#define BATCH 4096
#define HID   2048
#define NT    64          // K-tiles of 64

typedef __attribute__((ext_vector_type(8))) short bf16x8;
typedef __attribute__((ext_vector_type(4))) float f32x4;

__device__ __forceinline__ unsigned short f2bf(float f) {
  union { float f; unsigned u; } a; a.f = f;
  unsigned u = a.u;
  return (unsigned short)((u + 0x7FFFu + ((u >> 16) & 1u)) >> 16);  // RNE
}

__device__ __forceinline__ void gload_lds16(const void* g, void* l) {
  __builtin_amdgcn_global_load_lds((const __attribute__((address_space(1))) void*)g,
                                   (__attribute__((address_space(3))) void*)l, 16, 0, 0);
}

#define SCHED0() __builtin_amdgcn_sched_barrier(0)
#define SBAR()  do { SCHED0(); __builtin_amdgcn_s_barrier(); SCHED0(); } while (0)
#define WAITV(N) do { SCHED0(); asm volatile("s_waitcnt vmcnt(" #N ")" ::: "memory"); SCHED0(); } while (0)
#define WAITL(N) do { SCHED0(); asm volatile("s_waitcnt lgkmcnt(" #N ")" ::: "memory"); SCHED0(); } while (0)
#define DSR(dst, adr, IMM) asm volatile("ds_read_b128 %0, %1 offset:" #IMM : "=v"(dst) : "v"(adr))

// current-cluster A M-half1 frags (single-buffered, read early in own cluster)
#define RD_A2_LO(ADR) do { DSR(a2[0],ADR,4096); DSR(a2[1],ADR,5120); DSR(a2[2],ADR,6144); DSR(a2[3],ADR,7168); } while (0)
#define RD_A2_HI(ADR) do { DSR(a2[0],ADR,36864); DSR(a2[1],ADR,37888); DSR(a2[2],ADR,38912); DSR(a2[3],ADR,39936); } while (0)
// next-cluster A M-half0 + B frags (double-buffered reg sets)
#define RD_N_LO(AADR,BADR,A1,BF) do { \
  DSR(A1[0],AADR,0); DSR(A1[1],AADR,1024); DSR(A1[2],AADR,2048); DSR(A1[3],AADR,3072); \
  DSR(BF[0],BADR,0); DSR(BF[1],BADR,1024); DSR(BF[2],BADR,2048); DSR(BF[3],BADR,3072); } while (0)
#define RD_N_HI(AADR,BADR,A1,BF) do { \
  DSR(A1[0],AADR,32768); DSR(A1[1],AADR,33792); DSR(A1[2],AADR,34816); DSR(A1[3],AADR,35840); \
  DSR(BF[0],BADR,32768); DSR(BF[1],BADR,33792); DSR(BF[2],BADR,34816); DSR(BF[3],BADR,35840); } while (0)

#define MFMA_LO(A1, BF) do { _Pragma("unroll") \
  for (int m_ = 0; m_ < 4; m_++) { _Pragma("unroll") \
    for (int n_ = 0; n_ < 4; n_++) \
      acc[m_][n_] = __builtin_amdgcn_mfma_f32_16x16x32_bf16(A1[m_], BF[n_], acc[m_][n_], 0, 0, 0); } } while (0)
#define MFMA_HI(BF) do { _Pragma("unroll") \
  for (int m_ = 0; m_ < 4; m_++) { _Pragma("unroll") \
    for (int n_ = 0; n_ < 4; n_++) \
      acc[4+m_][n_] = __builtin_amdgcn_mfma_f32_16x16x32_bf16(a2[m_], BF[n_], acc[4+m_][n_], 0, 0, 0); } } while (0)

// stage one 32KB group (A+B, 32 K-cols) for group dest DOF = buf*65536 + half*32768
#define STAGE_G(KOFF, DOF) do { \
  gload_lds16(pA + (KOFF), dA + (DOF)); \
  gload_lds16(pA + 128*4096 + (KOFF), dA + (DOF) + 8192); \
  gload_lds16(pB + (KOFF), dA + (DOF) + 16384); \
  gload_lds16(pB + 32*4096 + (KOFF), dA + (DOF) + 16384 + 8192); } while (0)

// one pipelined cluster: TOPV drains gloads for the reads issued here; prev-cluster
// reads (lgkm 0) are the MFMA operands. Issue order: a2 DSRs (first 4 DS ops ->
// WAITL(8) semantics), then the 4 stage gloads (earliest HBM start; vmcnt-only),
// then the 8 next-cluster DSRs; all drain under the 32 MFMAs.
#define SLOT(TOPV, RDA2CALL, RDNCALL, STAGECALL, MA1, MBF) do { \
  TOPV; SBAR(); WAITL(0); \
  RDA2CALL; \
  STAGECALL; \
  RDNCALL; \
  SCHED0(); \
  __builtin_amdgcn_s_setprio(1); MFMA_LO(MA1, MBF); __builtin_amdgcn_s_setprio(0); \
  WAITL(8); \
  __builtin_amdgcn_s_setprio(1); MFMA_HI(MBF); __builtin_amdgcn_s_setprio(0); \
} while (0)

// ---- fp32 -> bf16 pack (verified r2): A=[x|h] 4096x4096; Wbf gate-major 8192x4096
__global__ __launch_bounds__(256) void convert_kernel(
    const float* __restrict__ x, const float* __restrict__ h,
    const float* __restrict__ wii, const float* __restrict__ wif,
    const float* __restrict__ wig, const float* __restrict__ wio,
    const float* __restrict__ whi, const float* __restrict__ whf,
    const float* __restrict__ whg, const float* __restrict__ who,
    unsigned short* __restrict__ Abf, unsigned short* __restrict__ Wbf) {
  int seg = blockIdx.y;
  const float* src;
  unsigned short* dst;
  int ofs;
  size_t rofs;
  if (seg < 4) {
    src = (seg < 2) ? x : h;
    dst = Abf;
    ofs = (seg < 2) ? 0 : 2048;
    rofs = (seg & 1) ? 2048 : 0;
    src += rofs * 2048;
  } else {
    int g = (seg - 4) & 3;
    dst = Wbf + (size_t)g * 2048 * 4096;
    ofs = (seg >= 8) ? 2048 : 0;
    rofs = 0;
    switch (seg) {
      case 4: src = wii; break; case 5: src = wif; break;
      case 6: src = wig; break; case 7: src = wio; break;
      case 8: src = whi; break; case 9: src = whf; break;
      case 10: src = whg; break; default: src = who; break;
    }
  }
  size_t idx = (size_t)blockIdx.x * 256 + threadIdx.x;
  size_t e = idx * 4;
  int n = (int)(e >> 11);
  int k = (int)(e & 2047);
  float4 v = *(const float4*)(src + e);
  ushort4 o;
  o.x = f2bf(v.x); o.y = f2bf(v.y); o.z = f2bf(v.z); o.w = f2bf(v.w);
  *(ushort4*)(dst + (rofs + (size_t)n) * 4096 + ofs + k) = o;
}

// ---- 256x256-tile LSTM GEMM, software-pipelined clusters (T2+T3+T4+T5)
// Cluster c (half-K-tile): MFMA uses regs read at c-1; reads for c+1 and the
// stage for group c+3 issue BEFORE the MFMAs and drain under them.
__global__ __launch_bounds__(512, 2) void lstm_gemm8(
    const unsigned short* __restrict__ Abf, const unsigned short* __restrict__ Wbf,
    const float* __restrict__ c_in,
    const float* __restrict__ bias_i, const float* __restrict__ bias_f,
    const float* __restrict__ bias_g, const float* __restrict__ bias_o,
    float* __restrict__ out) {
  // 2 dbuf x [A-lo, B-lo, A-hi, B-hi] x 16KB = 128KB
  __shared__ unsigned short lds[2][4][256 * 32];

  int tid = threadIdx.x;
  int lane = tid & 63;
  int wid = tid >> 6;            // 0..7
  int wr = wid >> 2;             // M-half (128 rows)
  int wc = wid & 3;              // N-quarter (64 packed rows)
  int lrow = lane & 15;
  int qh = lane >> 4;            // 16B chunk within 32-k part

  int bid = blockIdx.x;          // 512 blocks = 16 mt x 32 bn
  int xcd = bid & 7;
  int t7 = bid >> 3;
  int mt = t7 & 15;
  int bn = xcd * 4 + (t7 >> 4);  // each XCD owns 4 bn columns
  int m0 = mt * 256;

  // staging source addresses (linear LDS dest; inverse-swizzled global chunk)
  int r0 = tid >> 2, cc0 = tid & 3;
  int ccs0 = cc0 ^ ((r0 >> 1) & 3);
  const unsigned short* pA = Abf + (size_t)(m0 + r0) * 4096 + ccs0 * 8;
  int g0 = (r0 >> 4) & 3;
  int jw = bn * 64 + ((r0 >> 6) & 3) * 16 + (r0 & 15);
  const unsigned short* pB = Wbf + ((size_t)g0 * 2048 + jw) * 4096 + ccs0 * 8;

  char* L0 = (char*)&lds[0][0][0];
  char* dA = L0 + tid * 16;
  unsigned ldsOff = (unsigned)(size_t)(__attribute__((address_space(3))) char*)L0;

  int arow0 = wr * 128 + lrow;
  int brow0 = wc * 64 + lrow;
  unsigned qsA = ((unsigned)(qh ^ ((arow0 >> 1) & 3))) << 4;
  unsigned qsB = ((unsigned)(qh ^ ((brow0 >> 1) & 3))) << 4;
  unsigned a0 = ldsOff + (unsigned)arow0 * 64 + qsA;            // A buf0 base
  unsigned b0 = ldsOff + 16384u + (unsigned)brow0 * 64 + qsB;   // B buf0 base
  unsigned a1v = a0 + 65536u;                                   // A buf1
  unsigned b1v = b0 + 65536u;                                   // B buf1

  f32x4 acc[8][4];
  #pragma unroll
  for (int a = 0; a < 8; a++)
    #pragma unroll
    for (int b = 0; b < 4; b++) acc[a][b] = (f32x4){0.f, 0.f, 0.f, 0.f};

  bf16x8 a1A[4], bfA[4], a1B[4], bfB[4], a2[4];

  // ---- prologue: stage groups g0(buf0.lo,k0), g1(buf0.hi,k32), g2(buf1.lo,k64)
  STAGE_G(0, 0);
  STAGE_G(32, 32768);
  STAGE_G(64, 65536);
  WAITV(8);                      // g0 landed
  SBAR();
  RD_N_LO(a0, b0, a1A, bfA);     // reads m(0) -> setA

  // ---- main loop: 31 iters x 4 clusters = clusters 0..123 (tiles 0..61)
  for (int i = 0; i < 31; ++i) {
    int kb = i * 128;
    // c=4i+0: MFMA buf0.lo(setA); next buf0.hi->setB; stage buf1.hi @ kb+96
    SLOT(WAITV(4), RD_A2_LO(a0), RD_N_HI(a0, b0, a1B, bfB), STAGE_G(kb + 96, 98304), a1A, bfA);
    // c=4i+1: MFMA buf0.hi(setB); next buf1.lo->setA; stage buf0.lo @ kb+128
    SLOT(WAITV(4), RD_A2_HI(a0), RD_N_LO(a1v, b1v, a1A, bfA), STAGE_G(kb + 128, 0), a1B, bfB);
    // c=4i+2: MFMA buf1.lo(setA); next buf1.hi->setB; stage buf0.hi @ kb+160
    SLOT(WAITV(4), RD_A2_LO(a1v), RD_N_HI(a1v, b1v, a1B, bfB), STAGE_G(kb + 160, 32768), a1A, bfA);
    // c=4i+3: MFMA buf1.hi(setB); next buf0.lo->setA; stage buf1.lo @ kb+192
    SLOT(WAITV(4), RD_A2_HI(a1v), RD_N_LO(a0, b0, a1A, bfA), STAGE_G(kb + 192, 65536), a1B, bfB);
  }

  // ---- tail: clusters 124..127 (tiles 62,63)
  // c=124: stage last group g127 (buf1.hi, k=4064)
  SLOT(WAITV(4), RD_A2_LO(a0), RD_N_HI(a0, b0, a1B, bfB), STAGE_G(4064, 98304), a1A, bfA);
  // c=125: no stage; vmcnt(4) drains g126 (buf1.lo)
  SLOT(WAITV(4), RD_A2_HI(a0), RD_N_LO(a1v, b1v, a1A, bfA), (void)0, a1B, bfB);
  // c=126: vmcnt(0) drains g127 (buf1.hi) before reading it
  SLOT(WAITV(0), RD_A2_LO(a1v), RD_N_HI(a1v, b1v, a1B, bfB), (void)0, a1A, bfA);
  // c=127: final cluster, no next reads
  WAITL(0);
  RD_A2_HI(a1v);
  SCHED0();
  __builtin_amdgcn_s_setprio(1); MFMA_LO(a1B, bfB); __builtin_amdgcn_s_setprio(0);
  WAITL(0);
  __builtin_amdgcn_s_setprio(1); MFMA_HI(bfB); __builtin_amdgcn_s_setprio(0);

  // ---- epilogue: all 4 gates (n-index) for (m, j) are thread-local
  int j = bn * 64 + wc * 16 + lrow;
  float bi = bias_i[j], bff = bias_f[j], bgg = bias_g[j], bo = bias_o[j];
  int rbase = m0 + wr * 128 + qh * 4;
  #pragma unroll
  for (int mf = 0; mf < 8; mf++) {
    #pragma unroll
    for (int qq = 0; qq < 4; qq++) {
      int m = rbase + mf * 16 + qq;     // C/D: col=lane&15, row=(lane>>4)*4+qq
      size_t off = (size_t)m * HID + j;
      float gi = acc[mf][0][qq] + bi;
      float gf = acc[mf][1][qq] + bff;
      float gg = acc[mf][2][qq] + bgg;
      float go = acc[mf][3][qq] + bo;
      float iv = 1.f / (1.f + __expf(-gi));
      float fv = 1.f / (1.f + __expf(-gf));
      float gv = tanhf(gg);
      float ov = 1.f / (1.f + __expf(-go));
      float cn = fv * c_in[off] + iv * gv;
      float hn = ov * tanhf(cn);
      out[off] = hn;
      out[(size_t)BATCH * HID + off] = cn;
    }
  }
}

// ---- fallback (no workspace): round-3 verified 128-tile reg-staged kernel
__global__ __launch_bounds__(256) void lstm_gemm_fb(
    const float* __restrict__ x, const float* __restrict__ h,
    const float* __restrict__ wii, const float* __restrict__ wif,
    const float* __restrict__ wig, const float* __restrict__ wio,
    const float* __restrict__ whi, const float* __restrict__ whf,
    const float* __restrict__ whg, const float* __restrict__ who,
    const float* __restrict__ c_in,
    const float* __restrict__ bias_i, const float* __restrict__ bias_f,
    const float* __restrict__ bias_g, const float* __restrict__ bias_o,
    float* __restrict__ out) {
  __shared__ unsigned short Ald[128 * 64];
  __shared__ unsigned short Bld[128 * 64];
  int tid = threadIdx.x;
  int lane = tid & 63;
  int wid = tid >> 6;
  int wr = wid >> 1, wc = wid & 1;
  int bid = blockIdx.x;
  int swz = (bid & 7) * 256 + (bid >> 3);
  int mt = swz & 31;
  int ht = swz >> 5;
  int m0 = mt * 128;
  int j0 = ht * 32;
  f32x4 acc[4][4];
  #pragma unroll
  for (int a = 0; a < 4; a++)
    #pragma unroll
    for (int b = 0; b < 4; b++) acc[a][b] = (f32x4){0.f, 0.f, 0.f, 0.f};
  int lrow = lane & 15;
  int lsw = lrow & 7;
  int qbase = lane >> 4;
  for (int kt = 0; kt < 64; kt++) {
    int k0 = kt * 64;
    const float* Asrc = (k0 < 2048) ? x : h;
    int ka = k0 & 2047;
    #pragma unroll
    for (int i = 0; i < 4; i++) {
      int c = i * 256 + tid;
      int r = c >> 3, cc = c & 7;
      int ccs = cc ^ (r & 7);
      const float* s = Asrc + (size_t)(m0 + r) * 2048 + ka + ccs * 8;
      float4 v0 = *(const float4*)s;
      float4 v1 = *(const float4*)(s + 4);
      bf16x8 pk;
      pk[0] = (short)f2bf(v0.x); pk[1] = (short)f2bf(v0.y);
      pk[2] = (short)f2bf(v0.z); pk[3] = (short)f2bf(v0.w);
      pk[4] = (short)f2bf(v1.x); pk[5] = (short)f2bf(v1.y);
      pk[6] = (short)f2bf(v1.z); pk[7] = (short)f2bf(v1.w);
      *(bf16x8*)((char*)Ald + (size_t)c * 16) = pk;
    }
    #pragma unroll
    for (int i = 0; i < 4; i++) {
      int c = i * 256 + tid;
      int rb = c >> 3, cc = c & 7;
      int ccs = cc ^ (rb & 7);
      int g = rb >> 5, jj = rb & 31;
      const float* Bsrc;
      if (k0 < 2048) Bsrc = (g == 0) ? wii : (g == 1) ? wif : (g == 2) ? wig : wio;
      else           Bsrc = (g == 0) ? whi : (g == 1) ? whf : (g == 2) ? whg : who;
      const float* s = Bsrc + (size_t)(j0 + jj) * 2048 + ka + ccs * 8;
      float4 v0 = *(const float4*)s;
      float4 v1 = *(const float4*)(s + 4);
      bf16x8 pk;
      pk[0] = (short)f2bf(v0.x); pk[1] = (short)f2bf(v0.y);
      pk[2] = (short)f2bf(v0.z); pk[3] = (short)f2bf(v0.w);
      pk[4] = (short)f2bf(v1.x); pk[5] = (short)f2bf(v1.y);
      pk[6] = (short)f2bf(v1.z); pk[7] = (short)f2bf(v1.w);
      *(bf16x8*)((char*)Bld + (size_t)c * 16) = pk;
    }
    __syncthreads();
    #pragma unroll
    for (int ks = 0; ks < 2; ks++) {
      int q = ks * 4 + qbase;
      int qs8 = (q ^ lsw) * 8;
      bf16x8 af[4], bg[4];
      #pragma unroll
      for (int mf = 0; mf < 4; mf++)
        af[mf] = *(const bf16x8*)&Ald[(wr * 64 + mf * 16 + lrow) * 64 + qs8];
      #pragma unroll
      for (int g = 0; g < 4; g++)
        bg[g] = *(const bf16x8*)&Bld[(g * 32 + wc * 16 + lrow) * 64 + qs8];
      #pragma unroll
      for (int mf = 0; mf < 4; mf++)
        #pragma unroll
        for (int g = 0; g < 4; g++)
          acc[mf][g] = __builtin_amdgcn_mfma_f32_16x16x32_bf16(af[mf], bg[g], acc[mf][g], 0, 0, 0);
    }
    __syncthreads();
  }
  int j = j0 + wc * 16 + lrow;
  float bi = bias_i[j], bff = bias_f[j], bgg = bias_g[j], bo = bias_o[j];
  int rbase = m0 + wr * 64 + (lane >> 4) * 4;
  #pragma unroll
  for (int mf = 0; mf < 4; mf++) {
    #pragma unroll
    for (int q = 0; q < 4; q++) {
      int m = rbase + mf * 16 + q;
      size_t off = (size_t)m * HID + j;
      float gi = acc[mf][0][q] + bi;
      float gf = acc[mf][1][q] + bff;
      float gg = acc[mf][2][q] + bgg;
      float go = acc[mf][3][q] + bo;
      float iv = 1.f / (1.f + __expf(-gi));
      float fv = 1.f / (1.f + __expf(-gf));
      float gv = tanhf(gg);
      float ov = 1.f / (1.f + __expf(-go));
      float cn = fv * c_in[off] + iv * gv;
      float hn = ov * tanhf(cn);
      out[off] = hn;
      out[(size_t)BATCH * HID + off] = cn;
    }
  }
}

extern "C" void kernel_launch(void* const* d_in, const int* in_sizes, int n_in,
                              void* d_out, int out_size, void* d_ws, size_t ws_size,
                              hipStream_t stream) {
  const float* x   = (const float*)d_in[0];
  const float* h   = (const float*)d_in[1];
  const float* c   = (const float*)d_in[2];
  const float* wii = (const float*)d_in[3];
  const float* wif = (const float*)d_in[4];
  const float* wig = (const float*)d_in[5];
  const float* wio = (const float*)d_in[6];
  const float* whi = (const float*)d_in[7];
  const float* whf = (const float*)d_in[8];
  const float* whg = (const float*)d_in[9];
  const float* who = (const float*)d_in[10];
  const float* bi  = (const float*)d_in[11];
  const float* bf  = (const float*)d_in[12];
  const float* bg  = (const float*)d_in[13];
  const float* bo  = (const float*)d_in[14];
  float* out = (float*)d_out;

  size_t needA = (size_t)4096 * 4096 * 2;
  size_t needW = (size_t)8192 * 4096 * 2;

  if (ws_size >= needA + needW) {
    unsigned short* Abf = (unsigned short*)d_ws;
    unsigned short* Wbf = (unsigned short*)((char*)d_ws + needA);
    convert_kernel<<<dim3(4096, 12), 256, 0, stream>>>(
        x, h, wii, wif, wig, wio, whi, whf, whg, who, Abf, Wbf);
    lstm_gemm8<<<512, 512, 0, stream>>>(Abf, Wbf, c, bi, bf, bg, bo, out);
  } else {
    lstm_gemm_fb<<<2048, 256, 0, stream>>>(
        x, h, wii, wif, wig, wio, whi, whf, whg, who,
        c, bi, bf, bg, bo, out);
  }
}

// Round 18
// 314.159 us; speedup vs baseline: 1.0055x; 1.0055x over previous
//
#include <hip/hip_runtime.h>
#include <cstdint>
#include <cstddef>

#define BATCH 4096
#define HID   2048
#define NT    64          // K-tiles of 64

typedef __attribute__((ext_vector_type(8))) short bf16x8;
typedef __attribute__((ext_vector_type(4))) float f32x4;

__device__ __forceinline__ unsigned short f2bf(float f) {
  union { float f; unsigned u; } a; a.f = f;
  unsigned u = a.u;
  return (unsigned short)((u + 0x7FFFu + ((u >> 16) & 1u)) >> 16);  // RNE
}

__device__ __forceinline__ void gload_lds16(const void* g, void* l) {
  __builtin_amdgcn_global_load_lds((const __attribute__((address_space(1))) void*)g,
                                   (__attribute__((address_space(3))) void*)l, 16, 0, 0);
}

#define SCHED0() __builtin_amdgcn_sched_barrier(0)
#define SBAR()  do { SCHED0(); __builtin_amdgcn_s_barrier(); SCHED0(); } while (0)
#define WAITV(N) do { SCHED0(); asm volatile("s_waitcnt vmcnt(" #N ")" ::: "memory"); SCHED0(); } while (0)
#define WAITL(N) do { SCHED0(); asm volatile("s_waitcnt lgkmcnt(" #N ")" ::: "memory"); SCHED0(); } while (0)
#define DSR(dst, adr, IMM) asm volatile("ds_read_b128 %0, %1 offset:" #IMM : "=v"(dst) : "v"(adr))

// current-cluster A M-half1 frags (single-buffered, read early in own cluster)
#define RD_A2_LO(ADR) do { DSR(a2[0],ADR,4096); DSR(a2[1],ADR,5120); DSR(a2[2],ADR,6144); DSR(a2[3],ADR,7168); } while (0)
#define RD_A2_HI(ADR) do { DSR(a2[0],ADR,36864); DSR(a2[1],ADR,37888); DSR(a2[2],ADR,38912); DSR(a2[3],ADR,39936); } while (0)
// next-cluster A M-half0 + B frags (double-buffered reg sets)
#define RD_N_LO(AADR,BADR,A1,BF) do { \
  DSR(A1[0],AADR,0); DSR(A1[1],AADR,1024); DSR(A1[2],AADR,2048); DSR(A1[3],AADR,3072); \
  DSR(BF[0],BADR,0); DSR(BF[1],BADR,1024); DSR(BF[2],BADR,2048); DSR(BF[3],BADR,3072); } while (0)
#define RD_N_HI(AADR,BADR,A1,BF) do { \
  DSR(A1[0],AADR,32768); DSR(A1[1],AADR,33792); DSR(A1[2],AADR,34816); DSR(A1[3],AADR,35840); \
  DSR(BF[0],BADR,32768); DSR(BF[1],BADR,33792); DSR(BF[2],BADR,34816); DSR(BF[3],BADR,35840); } while (0)

#define MFMA_LO(A1, BF) do { _Pragma("unroll") \
  for (int m_ = 0; m_ < 4; m_++) { _Pragma("unroll") \
    for (int n_ = 0; n_ < 4; n_++) \
      acc[m_][n_] = __builtin_amdgcn_mfma_f32_16x16x32_bf16(A1[m_], BF[n_], acc[m_][n_], 0, 0, 0); } } while (0)
#define MFMA_HI(BF) do { _Pragma("unroll") \
  for (int m_ = 0; m_ < 4; m_++) { _Pragma("unroll") \
    for (int n_ = 0; n_ < 4; n_++) \
      acc[4+m_][n_] = __builtin_amdgcn_mfma_f32_16x16x32_bf16(a2[m_], BF[n_], acc[4+m_][n_], 0, 0, 0); } } while (0)

// stage one 32KB group (A+B, 32 K-cols) for group dest DOF = buf*65536 + half*32768
#define STAGE_G(KOFF, DOF) do { \
  gload_lds16(pA + (KOFF), dA + (DOF)); \
  gload_lds16(pA + 128*4096 + (KOFF), dA + (DOF) + 8192); \
  gload_lds16(pB + (KOFF), dA + (DOF) + 16384); \
  gload_lds16(pB + 32*4096 + (KOFF), dA + (DOF) + 16384 + 8192); } while (0)

// one pipelined cluster: TOPV drains gloads for the reads issued here; prev-cluster
// reads (lgkm 0) are the MFMA operands. Issue order: a2 DSRs (first 4 DS ops ->
// WAITL(8) semantics), then the 4 stage gloads (earliest HBM start; vmcnt-only),
// then the 8 next-cluster DSRs; all drain under the 32 MFMAs.
#define SLOT(TOPV, RDA2CALL, RDNCALL, STAGECALL, MA1, MBF) do { \
  TOPV; SBAR(); WAITL(0); \
  RDA2CALL; \
  STAGECALL; \
  RDNCALL; \
  SCHED0(); \
  __builtin_amdgcn_s_setprio(1); MFMA_LO(MA1, MBF); __builtin_amdgcn_s_setprio(0); \
  WAITL(8); \
  __builtin_amdgcn_s_setprio(1); MFMA_HI(MBF); __builtin_amdgcn_s_setprio(0); \
} while (0)

// ---- fp32 -> bf16 pack (verified r2): A=[x|h] 4096x4096; Wbf gate-major 8192x4096
__global__ __launch_bounds__(256) void convert_kernel(
    const float* __restrict__ x, const float* __restrict__ h,
    const float* __restrict__ wii, const float* __restrict__ wif,
    const float* __restrict__ wig, const float* __restrict__ wio,
    const float* __restrict__ whi, const float* __restrict__ whf,
    const float* __restrict__ whg, const float* __restrict__ who,
    unsigned short* __restrict__ Abf, unsigned short* __restrict__ Wbf) {
  int seg = blockIdx.y;
  const float* src;
  unsigned short* dst;
  int ofs;
  size_t rofs;
  if (seg < 4) {
    src = (seg < 2) ? x : h;
    dst = Abf;
    ofs = (seg < 2) ? 0 : 2048;
    rofs = (seg & 1) ? 2048 : 0;
    src += rofs * 2048;
  } else {
    int g = (seg - 4) & 3;
    dst = Wbf + (size_t)g * 2048 * 4096;
    ofs = (seg >= 8) ? 2048 : 0;
    rofs = 0;
    switch (seg) {
      case 4: src = wii; break; case 5: src = wif; break;
      case 6: src = wig; break; case 7: src = wio; break;
      case 8: src = whi; break; case 9: src = whf; break;
      case 10: src = whg; break; default: src = who; break;
    }
  }
  size_t idx = (size_t)blockIdx.x * 256 + threadIdx.x;
  size_t e = idx * 4;
  int n = (int)(e >> 11);
  int k = (int)(e & 2047);
  float4 v = *(const float4*)(src + e);
  ushort4 o;
  o.x = f2bf(v.x); o.y = f2bf(v.y); o.z = f2bf(v.z); o.w = f2bf(v.w);
  *(ushort4*)(dst + (rofs + (size_t)n) * 4096 + ofs + k) = o;
}

// ---- 256x256-tile LSTM GEMM, software-pipelined clusters (T2+T3+T4+T5)
// Cluster c (half-K-tile): MFMA uses regs read at c-1; reads for c+1 and the
// stage for group c+3 issue BEFORE the MFMAs and drain under them.
__global__ __launch_bounds__(512, 2) void lstm_gemm8(
    const unsigned short* __restrict__ Abf, const unsigned short* __restrict__ Wbf,
    const float* __restrict__ c_in,
    const float* __restrict__ bias_i, const float* __restrict__ bias_f,
    const float* __restrict__ bias_g, const float* __restrict__ bias_o,
    float* __restrict__ out) {
  // 2 dbuf x [A-lo, B-lo, A-hi, B-hi] x 16KB = 128KB
  __shared__ unsigned short lds[2][4][256 * 32];

  int tid = threadIdx.x;
  int lane = tid & 63;
  int wid = tid >> 6;            // 0..7
  int wr = wid >> 2;             // M-half (128 rows)
  int wc = wid & 3;              // N-quarter (64 packed rows)
  int lrow = lane & 15;
  int qh = lane >> 4;            // 16B chunk within 32-k part

  int bid = blockIdx.x;          // 512 blocks = 16 mt x 32 bn
  int xcd = bid & 7;
  int t7 = bid >> 3;
  int mt = t7 & 15;
  int bn = xcd * 4 + (t7 >> 4);  // each XCD owns 4 bn columns
  int m0 = mt * 256;

  // staging source addresses (linear LDS dest; inverse-swizzled global chunk)
  int r0 = tid >> 2, cc0 = tid & 3;
  int ccs0 = cc0 ^ ((r0 >> 1) & 3);
  const unsigned short* pA = Abf + (size_t)(m0 + r0) * 4096 + ccs0 * 8;
  int g0 = (r0 >> 4) & 3;
  int jw = bn * 64 + ((r0 >> 6) & 3) * 16 + (r0 & 15);
  const unsigned short* pB = Wbf + ((size_t)g0 * 2048 + jw) * 4096 + ccs0 * 8;

  char* L0 = (char*)&lds[0][0][0];
  char* dA = L0 + tid * 16;
  unsigned ldsOff = (unsigned)(size_t)(__attribute__((address_space(3))) char*)L0;

  int arow0 = wr * 128 + lrow;
  int brow0 = wc * 64 + lrow;
  unsigned qsA = ((unsigned)(qh ^ ((arow0 >> 1) & 3))) << 4;
  unsigned qsB = ((unsigned)(qh ^ ((brow0 >> 1) & 3))) << 4;
  unsigned a0 = ldsOff + (unsigned)arow0 * 64 + qsA;            // A buf0 base
  unsigned b0 = ldsOff + 16384u + (unsigned)brow0 * 64 + qsB;   // B buf0 base
  unsigned a1v = a0 + 65536u;                                   // A buf1
  unsigned b1v = b0 + 65536u;                                   // B buf1

  f32x4 acc[8][4];
  #pragma unroll
  for (int a = 0; a < 8; a++)
    #pragma unroll
    for (int b = 0; b < 4; b++) acc[a][b] = (f32x4){0.f, 0.f, 0.f, 0.f};

  bf16x8 a1A[4], bfA[4], a1B[4], bfB[4], a2[4];

  // ---- prologue: stage groups g0(buf0.lo,k0), g1(buf0.hi,k32), g2(buf1.lo,k64)
  STAGE_G(0, 0);
  STAGE_G(32, 32768);
  STAGE_G(64, 65536);
  WAITV(8);                      // g0 landed
  SBAR();
  RD_N_LO(a0, b0, a1A, bfA);     // reads m(0) -> setA

  // ---- main loop: 31 iters x 4 clusters = clusters 0..123 (tiles 0..61)
  for (int i = 0; i < 31; ++i) {
    int kb = i * 128;
    // c=4i+0: MFMA buf0.lo(setA); next buf0.hi->setB; stage buf1.hi @ kb+96
    SLOT(WAITV(4), RD_A2_LO(a0), RD_N_HI(a0, b0, a1B, bfB), STAGE_G(kb + 96, 98304), a1A, bfA);
    // c=4i+1: MFMA buf0.hi(setB); next buf1.lo->setA; stage buf0.lo @ kb+128
    SLOT(WAITV(4), RD_A2_HI(a0), RD_N_LO(a1v, b1v, a1A, bfA), STAGE_G(kb + 128, 0), a1B, bfB);
    // c=4i+2: MFMA buf1.lo(setA); next buf1.hi->setB; stage buf0.hi @ kb+160
    SLOT(WAITV(4), RD_A2_LO(a1v), RD_N_HI(a1v, b1v, a1B, bfB), STAGE_G(kb + 160, 32768), a1A, bfA);
    // c=4i+3: MFMA buf1.hi(setB); next buf0.lo->setA; stage buf1.lo @ kb+192
    SLOT(WAITV(4), RD_A2_HI(a1v), RD_N_LO(a0, b0, a1A, bfA), STAGE_G(kb + 192, 65536), a1B, bfB);
  }

  // ---- tail: clusters 124..127 (tiles 62,63)
  // c=124: stage last group g127 (buf1.hi, k=4064)
  SLOT(WAITV(4), RD_A2_LO(a0), RD_N_HI(a0, b0, a1B, bfB), STAGE_G(4064, 98304), a1A, bfA);
  // c=125: no stage; vmcnt(4) drains g126 (buf1.lo)
  SLOT(WAITV(4), RD_A2_HI(a0), RD_N_LO(a1v, b1v, a1A, bfA), (void)0, a1B, bfB);
  // c=126: vmcnt(0) drains g127 (buf1.hi) before reading it
  SLOT(WAITV(0), RD_A2_LO(a1v), RD_N_HI(a1v, b1v, a1B, bfB), (void)0, a1A, bfA);
  // c=127: final cluster, no next reads
  WAITL(0);
  RD_A2_HI(a1v);
  SCHED0();
  __builtin_amdgcn_s_setprio(1); MFMA_LO(a1B, bfB); __builtin_amdgcn_s_setprio(0);
  WAITL(0);
  __builtin_amdgcn_s_setprio(1); MFMA_HI(bfB); __builtin_amdgcn_s_setprio(0);

  // ---- epilogue: all 4 gates (n-index) for (m, j) are thread-local
  int j = bn * 64 + wc * 16 + lrow;
  float bi = bias_i[j], bff = bias_f[j], bgg = bias_g[j], bo = bias_o[j];
  int rbase = m0 + wr * 128 + qh * 4;
  #pragma unroll
  for (int mf = 0; mf < 8; mf++) {
    #pragma unroll
    for (int qq = 0; qq < 4; qq++) {
      int m = rbase + mf * 16 + qq;     // C/D: col=lane&15, row=(lane>>4)*4+qq
      size_t off = (size_t)m * HID + j;
      float gi = acc[mf][0][qq] + bi;
      float gf = acc[mf][1][qq] + bff;
      float gg = acc[mf][2][qq] + bgg;
      float go = acc[mf][3][qq] + bo;
      float iv = 1.f / (1.f + __expf(-gi));
      float fv = 1.f / (1.f + __expf(-gf));
      float gv = tanhf(gg);
      float ov = 1.f / (1.f + __expf(-go));
      float cn = fv * c_in[off] + iv * gv;
      float hn = ov * tanhf(cn);
      out[off] = hn;
      out[(size_t)BATCH * HID + off] = cn;
    }
  }
}

// ---- fallback (no workspace): round-3 verified 128-tile reg-staged kernel
__global__ __launch_bounds__(256) void lstm_gemm_fb(
    const float* __restrict__ x, const float* __restrict__ h,
    const float* __restrict__ wii, const float* __restrict__ wif,
    const float* __restrict__ wig, const float* __restrict__ wio,
    const float* __restrict__ whi, const float* __restrict__ whf,
    const float* __restrict__ whg, const float* __restrict__ who,
    const float* __restrict__ c_in,
    const float* __restrict__ bias_i, const float* __restrict__ bias_f,
    const float* __restrict__ bias_g, const float* __restrict__ bias_o,
    float* __restrict__ out) {
  __shared__ unsigned short Ald[128 * 64];
  __shared__ unsigned short Bld[128 * 64];
  int tid = threadIdx.x;
  int lane = tid & 63;
  int wid = tid >> 6;
  int wr = wid >> 1, wc = wid & 1;
  int bid = blockIdx.x;
  int swz = (bid & 7) * 256 + (bid >> 3);
  int mt = swz & 31;
  int ht = swz >> 5;
  int m0 = mt * 128;
  int j0 = ht * 32;
  f32x4 acc[4][4];
  #pragma unroll
  for (int a = 0; a < 4; a++)
    #pragma unroll
    for (int b = 0; b < 4; b++) acc[a][b] = (f32x4){0.f, 0.f, 0.f, 0.f};
  int lrow = lane & 15;
  int lsw = lrow & 7;
  int qbase = lane >> 4;
  for (int kt = 0; kt < 64; kt++) {
    int k0 = kt * 64;
    const float* Asrc = (k0 < 2048) ? x : h;
    int ka = k0 & 2047;
    #pragma unroll
    for (int i = 0; i < 4; i++) {
      int c = i * 256 + tid;
      int r = c >> 3, cc = c & 7;
      int ccs = cc ^ (r & 7);
      const float* s = Asrc + (size_t)(m0 + r) * 2048 + ka + ccs * 8;
      float4 v0 = *(const float4*)s;
      float4 v1 = *(const float4*)(s + 4);
      bf16x8 pk;
      pk[0] = (short)f2bf(v0.x); pk[1] = (short)f2bf(v0.y);
      pk[2] = (short)f2bf(v0.z); pk[3] = (short)f2bf(v0.w);
      pk[4] = (short)f2bf(v1.x); pk[5] = (short)f2bf(v1.y);
      pk[6] = (short)f2bf(v1.z); pk[7] = (short)f2bf(v1.w);
      *(bf16x8*)((char*)Ald + (size_t)c * 16) = pk;
    }
    #pragma unroll
    for (int i = 0; i < 4; i++) {
      int c = i * 256 + tid;
      int rb = c >> 3, cc = c & 7;
      int ccs = cc ^ (rb & 7);
      int g = rb >> 5, jj = rb & 31;
      const float* Bsrc;
      if (k0 < 2048) Bsrc = (g == 0) ? wii : (g == 1) ? wif : (g == 2) ? wig : wio;
      else           Bsrc = (g == 0) ? whi : (g == 1) ? whf : (g == 2) ? whg : who;
      const float* s = Bsrc + (size_t)(j0 + jj) * 2048 + ka + ccs * 8;
      float4 v0 = *(const float4*)s;
      float4 v1 = *(const float4*)(s + 4);
      bf16x8 pk;
      pk[0] = (short)f2bf(v0.x); pk[1] = (short)f2bf(v0.y);
      pk[2] = (short)f2bf(v0.z); pk[3] = (short)f2bf(v0.w);
      pk[4] = (short)f2bf(v1.x); pk[5] = (short)f2bf(v1.y);
      pk[6] = (short)f2bf(v1.z); pk[7] = (short)f2bf(v1.w);
      *(bf16x8*)((char*)Bld + (size_t)c * 16) = pk;
    }
    __syncthreads();
    #pragma unroll
    for (int ks = 0; ks < 2; ks++) {
      int q = ks * 4 + qbase;
      int qs8 = (q ^ lsw) * 8;
      bf16x8 af[4], bg[4];
      #pragma unroll
      for (int mf = 0; mf < 4; mf++)
        af[mf] = *(const bf16x8*)&Ald[(wr * 64 + mf * 16 + lrow) * 64 + qs8];
      #pragma unroll
      for (int g = 0; g < 4; g++)
        bg[g] = *(const bf16x8*)&Bld[(g * 32 + wc * 16 + lrow) * 64 + qs8];
      #pragma unroll
      for (int mf = 0; mf < 4; mf++)
        #pragma unroll
        for (int g = 0; g < 4; g++)
          acc[mf][g] = __builtin_amdgcn_mfma_f32_16x16x32_bf16(af[mf], bg[g], acc[mf][g], 0, 0, 0);
    }
    __syncthreads();
  }
  int j = j0 + wc * 16 + lrow;
  float bi = bias_i[j], bff = bias_f[j], bgg = bias_g[j], bo = bias_o[j];
  int rbase = m0 + wr * 64 + (lane >> 4) * 4;
  #pragma unroll
  for (int mf = 0; mf < 4; mf++) {
    #pragma unroll
    for (int q = 0; q < 4; q++) {
      int m = rbase + mf * 16 + q;
      size_t off = (size_t)m * HID + j;
      float gi = acc[mf][0][q] + bi;
      float gf = acc[mf][1][q] + bff;
      float gg = acc[mf][2][q] + bgg;
      float go = acc[mf][3][q] + bo;
      float iv = 1.f / (1.f + __expf(-gi));
      float fv = 1.f / (1.f + __expf(-gf));
      float gv = tanhf(gg);
      float ov = 1.f / (1.f + __expf(-go));
      float cn = fv * c_in[off] + iv * gv;
      float hn = ov * tanhf(cn);
      out[off] = hn;
      out[(size_t)BATCH * HID + off] = cn;
    }
  }
}

extern "C" void kernel_launch(void* const* d_in, const int* in_sizes, int n_in,
                              void* d_out, int out_size, void* d_ws, size_t ws_size,
                              hipStream_t stream) {
  const float* x   = (const float*)d_in[0];
  const float* h   = (const float*)d_in[1];
  const float* c   = (const float*)d_in[2];
  const float* wii = (const float*)d_in[3];
  const float* wif = (const float*)d_in[4];
  const float* wig = (const float*)d_in[5];
  const float* wio = (const float*)d_in[6];
  const float* whi = (const float*)d_in[7];
  const float* whf = (const float*)d_in[8];
  const float* whg = (const float*)d_in[9];
  const float* who = (const float*)d_in[10];
  const float* bi  = (const float*)d_in[11];
  const float* bf  = (const float*)d_in[12];
  const float* bg  = (const float*)d_in[13];
  const float* bo  = (const float*)d_in[14];
  float* out = (float*)d_out;

  size_t needA = (size_t)4096 * 4096 * 2;
  size_t needW = (size_t)8192 * 4096 * 2;

  if (ws_size >= needA + needW) {
    unsigned short* Abf = (unsigned short*)d_ws;
    unsigned short* Wbf = (unsigned short*)((char*)d_ws + needA);
    convert_kernel<<<dim3(4096, 12), 256, 0, stream>>>(
        x, h, wii, wif, wig, wio, whi, whf, whg, who, Abf, Wbf);
    lstm_gemm8<<<512, 512, 0, stream>>>(Abf, Wbf, c, bi, bf, bg, bo, out);
  } else {
    lstm_gemm_fb<<<2048, 256, 0, stream>>>(
        x, h, wii, wif, wig, wio, whi, whf, whg, who,
        c, bi, bf, bg, bo, out);
  }
}